// Round 11
// baseline (615.121 us; speedup 1.0000x reference)
//
#include <hip/hip_runtime.h>
#include <math.h>

// ---------------------------------------------------------------------------
// GraphConv (2-layer GAT) pipeline.
// GEMMs: split-bf16 MFMA (fp32 = hi+lo bf16 RNE pair along K, K'=2K).
// R11: traffic-minimal GEMM. R6/R10 both saturate ~5.5-6.5TB/s aggregate
//   memory service; R10 wasted it on 2x A re-read + per-block B re-reads.
//   Now 128x128 tile (A once per matrix, half the blocks -> half B re-read)
//   with BK=16 so dbuf LDS = 32KB (occupancy preserved). B pre-converted to
//   MFMA-fragment tiles [g][col] (g=lane>>4): linear global_load_lds staging,
//   conflict-free ds_reads. A staged [g][row] same way.
// ---------------------------------------------------------------------------

typedef __attribute__((ext_vector_type(8))) short bf16x8;
typedef __attribute__((ext_vector_type(4))) float f32x4;

__device__ __forceinline__ float gelu_exact(float x) {
    return 0.5f * x * (1.0f + erff(x * 0.70710678118654752f));
}

// round-to-nearest-even bf16; returns the f32 bit pattern of the rounded value
__device__ __forceinline__ unsigned int rne_bf16_bits(float f) {
    unsigned int u = __float_as_uint(f);
    unsigned int r = u + 0x7FFFu + ((u >> 16) & 1u);
    return r & 0xFFFF0000u;
}

// fp32 -> packed (hi bf16 | lo bf16<<16), RNE split.
__device__ __forceinline__ unsigned int packsplit(float f) {
    unsigned int hi_bits = rne_bf16_bits(f);
    float resid = f - __uint_as_float(hi_bits);
    unsigned int lo_bits = rne_bf16_bits(resid);
    return (hi_bits >> 16) | lo_bits;
}

__device__ __forceinline__ uint4 packsplit4(float4 v) {
    uint4 r;
    r.x = packsplit(v.x); r.y = packsplit(v.y);
    r.z = packsplit(v.z); r.w = packsplit(v.w);
    return r;
}

// ---------------------------------------------------------------------------
// conv_wt: W[K][Bcols] fp32 -> fragment tiles. Tile (ct,ks16) = 512 uint4:
//   entry g*128+col = packsplit of W[ks*16 + g*4 + 0..3][ct*128 + col].
// Tile is the exact LDS image: linear gload_lds, conflict-free ds_read
// (lane group g reads 16 consecutive uint4).
// ---------------------------------------------------------------------------
__global__ void conv_wt(const float* __restrict__ W, uint4* __restrict__ Bt4,
                        int K, int Bcols)
{
    int t = blockIdx.x * 256 + threadIdx.x;
    int KS = K >> 4;
    int nct = Bcols >> 7;
    int total = nct * KS * 512;
    if (t >= total) return;
    int e   = t & 511;
    int g   = e >> 7;
    int col = e & 127;
    int ts  = t >> 9;
    int ks  = ts % KS;
    int ct  = ts / KS;
    int gcol = ct * 128 + col;
    int krow = ks * 16 + g * 4;
    uint4 v;
    v.x = packsplit(W[(size_t)(krow + 0) * Bcols + gcol]);
    v.y = packsplit(W[(size_t)(krow + 1) * Bcols + gcol]);
    v.z = packsplit(W[(size_t)(krow + 2) * Bcols + gcol]);
    v.w = packsplit(W[(size_t)(krow + 3) * Bcols + gcol]);
    Bt4[t] = v;
}

// ---------------------------------------------------------------------------
// Split-bf16 MFMA GEMM, tile 128x128, BK=16 fp32, 4 waves (2x2 of 64x64),
// dbuf LDS 32KB. Per K-step per wave: 16 MFMA, 8 ds_read_b128, 2 gload_lds,
// 2 A float4 loads (issued 2 steps ahead), 2 ds_write_b128.
// MODE=0 (layer): blockIdx.y = col-tile ct; C[row*256 + ct*128 + col] = acc.
// MODE=1 (upscale): blockIdx.y = sel {img,txt};
//   C[ci[row]*256 + sel*128 + col] = gelu(acc + bias[col]).
// ---------------------------------------------------------------------------
template<int MODE>
__global__ __launch_bounds__(256)
void gemm128(const float* __restrict__ A0, const float* __restrict__ A1,
             const uint4* __restrict__ B0, const uint4* __restrict__ B1,
             const float* __restrict__ bias0, const float* __restrict__ bias1,
             float* __restrict__ C, const int* __restrict__ ci,
             int M, int K)
{
    __shared__ uint4 As4[2][512];   // [g][row] fragments, 8KB per buffer
    __shared__ uint4 Bs4[2][512];   // [g][col] fragments, 8KB per buffer

    const int tid  = threadIdx.x;
    const int lane = tid & 63;
    const int w    = tid >> 6;
    const int wr   = w >> 1, wc = w & 1;
    const int row0 = blockIdx.x * 128;
    const int KS   = K >> 4;

    const float* A; const uint4* Bt; const float* bias; int cb;
    if (MODE == 1) {
        int sel = blockIdx.y;
        A = sel ? A1 : A0; Bt = sel ? B1 : B0;
        bias = sel ? bias1 : bias0; cb = sel * 128;
    } else {
        A = A0; Bt = B0 + (size_t)blockIdx.y * KS * 512;
        bias = nullptr; cb = blockIdx.y * 128;
    }

    const int ag = tid & 3;            // fragment g owned for staging
    const int ar = tid >> 2;           // row 0..63 (p adds 64)

    f32x4 acc[4][4];
#pragma unroll
    for (int m = 0; m < 4; m++)
#pragma unroll
        for (int n = 0; n < 4; n++) acc[m][n] = (f32x4)0.f;

    auto loadA = [&](float4* rg, int ks) {
#pragma unroll
        for (int p = 0; p < 2; p++) {
            int gr = row0 + ar + p * 64;
            if (gr >= M) gr = M - 1;   // clamp: garbage rows never stored
            rg[p] = *(const float4*)&A[(size_t)gr * K + ks * 16 + ag * 4];
        }
    };
    auto writeA = [&](int buf, const float4* rg) {
#pragma unroll
        for (int p = 0; p < 2; p++)
            As4[buf][ag * 128 + ar + p * 64] = packsplit4(rg[p]);
    };
    auto stageB = [&](int buf, int ks) {
        const uint4* tp = Bt + (size_t)ks * 512;
#pragma unroll
        for (int q = 0; q < 2; q++) {
            int off = (w * 2 + q) * 64;          // uint4 units; 1KB per call
            __builtin_amdgcn_global_load_lds(
                (const __attribute__((address_space(1))) void*)(tp + off + lane),
                (__attribute__((address_space(3))) void*)(&Bs4[buf][off]),
                16, 0, 0);
        }
    };
    auto compute = [&](int buf) {
        const int g = lane >> 4;
        uint4 af[4], bfr[4];
#pragma unroll
        for (int m = 0; m < 4; m++)
            af[m] = As4[buf][g * 128 + wr * 64 + m * 16 + (lane & 15)];
#pragma unroll
        for (int n = 0; n < 4; n++)
            bfr[n] = Bs4[buf][g * 128 + wc * 64 + n * 16 + (lane & 15)];
#pragma unroll
        for (int m = 0; m < 4; m++)
#pragma unroll
            for (int n = 0; n < 4; n++)
                acc[m][n] = __builtin_amdgcn_mfma_f32_16x16x32_bf16(
                    *(const bf16x8*)&af[m], *(const bf16x8*)&bfr[n],
                    acc[m][n], 0, 0, 0);
    };

    // prologue: fill buffer 0; issue A(1) loads
    float4 aprev[2];
    loadA(aprev, 0);
    stageB(0, 0);
    writeA(0, aprev);
    if (KS > 1) loadA(aprev, 1);
    __syncthreads();

    int cur = 0;
    for (int ks = 0; ks < KS - 1; ++ks) {
        int nxt = cur ^ 1;
        stageB(nxt, ks + 1);                  // async B into other buffer
        float4 anew[2];
        if (ks + 2 < KS) loadA(anew, ks + 2); // A two steps ahead
        writeA(nxt, aprev);
        compute(cur);
        __syncthreads();
        aprev[0] = anew[0]; aprev[1] = anew[1];
        cur = nxt;
    }
    compute(cur);

    // epilogue: C/D layout col=lane&15, row=(lane>>4)*4+reg
#pragma unroll
    for (int m = 0; m < 4; m++) {
        int rbase = row0 + wr * 64 + m * 16 + ((lane >> 4) << 2);
#pragma unroll
        for (int n = 0; n < 4; n++) {
            int col = wc * 64 + n * 16 + (lane & 15);
#pragma unroll
            for (int j = 0; j < 4; j++) {
                int grow = rbase + j;
                if (grow >= M) continue;
                float v = acc[m][n][j];
                if (MODE == 1) {
                    v = gelu_exact(v + bias[col]);
                    C[(size_t)ci[grow] * 256 + cb + col] = v;
                } else {
                    C[(size_t)grow * 256 + cb + col] = v;
                }
            }
        }
    }
}

// per-node attention scores
__global__ __launch_bounds__(256)
void scores_kernel(const float* __restrict__ h, const float* __restrict__ asrc,
                   const float* __restrict__ adst, float* __restrict__ s_src,
                   float* __restrict__ s_dst, int N)
{
    int wave = threadIdx.x >> 6;
    int lane = threadIdx.x & 63;
    int n = blockIdx.x * 4 + wave;
    if (n >= N) return;
    float4 hv = *(const float4*)&h[(size_t)n * 256 + lane * 4];
    float4 av = *(const float4*)&asrc[lane * 4];
    float4 dv = *(const float4*)&adst[lane * 4];
    float ps = hv.x * av.x + hv.y * av.y + hv.z * av.z + hv.w * av.w;
    float pd = hv.x * dv.x + hv.y * dv.y + hv.z * dv.z + hv.w * dv.w;
#pragma unroll
    for (int off = 32; off; off >>= 1) {
        ps += __shfl_xor(ps, off);
        pd += __shfl_xor(pd, off);
    }
    if (lane == 0) { s_src[n] = ps; s_dst[n] = pd; }
}

// ---- CSR build ----
__global__ void init_cnt(int* cnt, int N) {
    int i = blockIdx.x * 256 + threadIdx.x;
    if (i < N) cnt[i] = 1;
}

__global__ void count_edges(const int* __restrict__ edges, int* cnt, int E) {
    int e = blockIdx.x * 256 + threadIdx.x;
    if (e < E) atomicAdd(&cnt[edges[2 * e + 1]], 1);
}

__global__ void scan1(const int* __restrict__ cnt, int* __restrict__ rs,
                      int* __restrict__ bsum, int N)
{
    __shared__ int sm[256];
    int tid = threadIdx.x;
    int i = blockIdx.x * 256 + tid;
    int v = (i < N) ? cnt[i] : 0;
    sm[tid] = v;
    __syncthreads();
    for (int off = 1; off < 256; off <<= 1) {
        int t = (tid >= off) ? sm[tid - off] : 0;
        __syncthreads();
        sm[tid] += t;
        __syncthreads();
    }
    if (i < N) rs[i] = sm[tid] - v;
    if (tid == 255) bsum[blockIdx.x] = sm[255];
}

__global__ void scan2(int* bsum, int nb) {
    __shared__ int sm[256];
    int tid = threadIdx.x;
    int v = (tid < nb) ? bsum[tid] : 0;
    sm[tid] = v;
    __syncthreads();
    for (int off = 1; off < 256; off <<= 1) {
        int t = (tid >= off) ? sm[tid - off] : 0;
        __syncthreads();
        sm[tid] += t;
        __syncthreads();
    }
    if (tid < nb) bsum[tid] = sm[tid] - v;
}

__global__ void scan3(int* __restrict__ rs, const int* __restrict__ bsum,
                      int N, int total)
{
    int i = blockIdx.x * 256 + threadIdx.x;
    if (i < N) rs[i] += bsum[i >> 8];
    if (i == 0) rs[N] = total;
}

__global__ void copy_cursor(const int* __restrict__ rs, int* __restrict__ cur, int N) {
    int i = blockIdx.x * 256 + threadIdx.x;
    if (i < N) cur[i] = rs[i];
}

__global__ void fill_csr(const int* __restrict__ edges, int* __restrict__ cur,
                         int* __restrict__ col, int E, int N)
{
    int i = blockIdx.x * 256 + threadIdx.x;
    if (i < E) {
        int s = edges[2 * i], d = edges[2 * i + 1];
        col[atomicAdd(&cur[d], 1)] = s;
    } else if (i < E + N) {
        int n = i - E;
        col[atomicAdd(&cur[n], 1)] = n;
    }
}

// ---------------------------------------------------------------------------
// attn: WAVE per dst node. No LDS, no barriers. 64 lanes cover 256 cols
// (float4/lane); weights lane-redundant; 4-deep independent h-row gathers.
// ---------------------------------------------------------------------------
template<int EPI>
__global__ __launch_bounds__(256)
void attn_kernel(const float* __restrict__ h, const float* __restrict__ s_src,
                 const float* __restrict__ s_dst, const int* __restrict__ rs,
                 const int* __restrict__ colv, const float* __restrict__ bias,
                 float* __restrict__ out, int N)
{
    const int wv   = threadIdx.x >> 6;
    const int lane = threadIdx.x & 63;
    const int n    = blockIdx.x * 4 + wv;
    if (n >= N) return;

    const float sd = s_dst[n];
    const int beg = rs[n], end = rs[n + 1];

    float4 acc = make_float4(0.f, 0.f, 0.f, 0.f);
    float den = 0.f;

    int i = beg;
    for (; i + 3 < end; i += 4) {
        int s0 = colv[i], s1 = colv[i + 1], s2 = colv[i + 2], s3 = colv[i + 3];
        float e0 = s_src[s0] + sd, e1 = s_src[s1] + sd;
        float e2 = s_src[s2] + sd, e3 = s_src[s3] + sd;
        e0 = (e0 > 0.f) ? e0 : 0.2f * e0;  e1 = (e1 > 0.f) ? e1 : 0.2f * e1;
        e2 = (e2 > 0.f) ? e2 : 0.2f * e2;  e3 = (e3 > 0.f) ? e3 : 0.2f * e3;
        float w0 = __expf(e0), w1 = __expf(e1), w2 = __expf(e2), w3 = __expf(e3);
        float4 h0 = *(const float4*)&h[(size_t)s0 * 256 + lane * 4];
        float4 h1 = *(const float4*)&h[(size_t)s1 * 256 + lane * 4];
        float4 h2 = *(const float4*)&h[(size_t)s2 * 256 + lane * 4];
        float4 h3 = *(const float4*)&h[(size_t)s3 * 256 + lane * 4];
        acc.x = fmaf(w0, h0.x, acc.x); acc.y = fmaf(w0, h0.y, acc.y);
        acc.z = fmaf(w0, h0.z, acc.z); acc.w = fmaf(w0, h0.w, acc.w);
        acc.x = fmaf(w1, h1.x, acc.x); acc.y = fmaf(w1, h1.y, acc.y);
        acc.z = fmaf(w1, h1.z, acc.z); acc.w = fmaf(w1, h1.w, acc.w);
        acc.x = fmaf(w2, h2.x, acc.x); acc.y = fmaf(w2, h2.y, acc.y);
        acc.z = fmaf(w2, h2.z, acc.z); acc.w = fmaf(w2, h2.w, acc.w);
        acc.x = fmaf(w3, h3.x, acc.x); acc.y = fmaf(w3, h3.y, acc.y);
        acc.z = fmaf(w3, h3.z, acc.z); acc.w = fmaf(w3, h3.w, acc.w);
        den += w0 + w1 + w2 + w3;
    }
    for (; i < end; ++i) {
        int s0 = colv[i];
        float e0 = s_src[s0] + sd;
        e0 = (e0 > 0.f) ? e0 : 0.2f * e0;
        float w0 = __expf(e0);
        float4 h0 = *(const float4*)&h[(size_t)s0 * 256 + lane * 4];
        acc.x = fmaf(w0, h0.x, acc.x); acc.y = fmaf(w0, h0.y, acc.y);
        acc.z = fmaf(w0, h0.z, acc.z); acc.w = fmaf(w0, h0.w, acc.w);
        den += w0;
    }

    float4 bv = *(const float4*)&bias[lane * 4];
    float inv = 1.f / den;
    float4 v;
    v.x = acc.x * inv + bv.x; v.y = acc.y * inv + bv.y;
    v.z = acc.z * inv + bv.z; v.w = acc.w * inv + bv.w;
    if (EPI == 1) {
        v.x = gelu_exact(v.x); v.y = gelu_exact(v.y);
        v.z = gelu_exact(v.z); v.w = gelu_exact(v.w);
    } else {
        v.x = fmaxf(v.x, 0.f); v.y = fmaxf(v.y, 0.f);
        v.z = fmaxf(v.z, 0.f); v.w = fmaxf(v.w, 0.f);
    }
    *(float4*)&out[(size_t)n * 256 + lane * 4] = v;
}

extern "C" void kernel_launch(void* const* d_in, const int* in_sizes, int n_in,
                              void* d_out, int out_size, void* d_ws, size_t ws_size,
                              hipStream_t stream)
{
    const float* img    = (const float*)d_in[0];
    const float* txt    = (const float*)d_in[1];
    const int*   ci     = (const int*)d_in[2];
    const int*   edges  = (const int*)d_in[3];
    const float* w_img  = (const float*)d_in[4];
    const float* b_img  = (const float*)d_in[5];
    const float* w_text = (const float*)d_in[6];
    const float* b_text = (const float*)d_in[7];
    const float* W0     = (const float*)d_in[8];
    const float* asrc0  = (const float*)d_in[9];
    const float* adst0  = (const float*)d_in[10];
    const float* bias0  = (const float*)d_in[11];
    const float* W1     = (const float*)d_in[12];
    const float* asrc1  = (const float*)d_in[13];
    const float* adst1  = (const float*)d_in[14];
    const float* bias1  = (const float*)d_in[15];

    const int N = in_sizes[2];
    const int E = in_sizes[3] / 2;
    const int T = E + N;

    float* fA   = (float*)d_ws;                    // node, later h1   N*256
    float* fB   = fA + (size_t)N * 256;            // out0             N*256
    float* sS   = fB + (size_t)N * 256;            // N
    float* sD   = sS + N;                          // N
    int*   rs   = (int*)(sD + N);                  // N+1
    int*   cur  = rs + (N + 1);                    // N
    int*   col  = cur + N;                         // E+N
    int*   bsum = col + T;                         // <=256
    uintptr_t bt0 = ((uintptr_t)(bsum + 256) + 63) & ~(uintptr_t)63;
    uint4* BtImg = (uint4*)bt0;                    // 48ks x 512 u4 (384KB)
    uint4* BtTxt = BtImg + 48 * 512;
    uint4* BtW0  = BtTxt + 48 * 512;               // 2ct x 16ks x 512 (256KB)
    uint4* BtW1  = BtW0  + 2 * 16 * 512;
    float* h0   = (float*)d_out;                   // N*256 scratch

    const int nb256 = (N + 255) / 256;
    const int nbT   = (T + 255) / 256;
    const int gm128 = (N + 127) / 128;             // 391

    conv_wt<<<(48 * 512 + 255) / 256, 256, 0, stream>>>(w_img,  BtImg, 768, 128);
    conv_wt<<<(48 * 512 + 255) / 256, 256, 0, stream>>>(w_text, BtTxt, 768, 128);
    conv_wt<<<(2 * 16 * 512 + 255) / 256, 256, 0, stream>>>(W0, BtW0, 256, 256);
    conv_wt<<<(2 * 16 * 512 + 255) / 256, 256, 0, stream>>>(W1, BtW1, 256, 256);

    // merged upscale GEMMs: grid (391, 2), y = sel {img, txt}
    gemm128<1><<<dim3(gm128, 2), 256, 0, stream>>>(
        img, txt, BtImg, BtTxt, b_img, b_text, fA, ci, N, 768);

    init_cnt<<<nb256, 256, 0, stream>>>(cur, N);
    count_edges<<<(E + 255) / 256, 256, 0, stream>>>(edges, cur, E);
    scan1<<<nb256, 256, 0, stream>>>(cur, rs, bsum, N);
    scan2<<<1, 256, 0, stream>>>(bsum, nb256);
    scan3<<<nb256, 256, 0, stream>>>(rs, bsum, N, T);
    copy_cursor<<<nb256, 256, 0, stream>>>(rs, cur, N);
    fill_csr<<<nbT, 256, 0, stream>>>(edges, cur, col, E, N);

    // ---- layer 0 ----
    gemm128<0><<<dim3(gm128, 2), 256, 0, stream>>>(
        fA, nullptr, BtW0, nullptr, nullptr, nullptr, h0, nullptr, N, 256);
    scores_kernel<<<(N + 3) / 4, 256, 0, stream>>>(h0, asrc0, adst0, sS, sD, N);
    attn_kernel<0><<<(N + 3) / 4, 256, 0, stream>>>(h0, sS, sD, rs, col, bias0, fB, N);

    // ---- layer 1 ----
    gemm128<0><<<dim3(gm128, 2), 256, 0, stream>>>(
        fB, nullptr, BtW1, nullptr, nullptr, nullptr, fA, nullptr, N, 256);
    scores_kernel<<<(N + 3) / 4, 256, 0, stream>>>(fA, asrc1, adst1, sS, sD, N);
    attn_kernel<1><<<(N + 3) / 4, 256, 0, stream>>>(fA, sS, sD, rs, col, bias1, (float*)d_out, N);
}

// Round 12
// 589.974 us; speedup vs baseline: 1.0426x; 1.0426x over previous
//
#include <hip/hip_runtime.h>
#include <math.h>

// ---------------------------------------------------------------------------
// GraphConv (2-layer GAT) pipeline.
// GEMMs: split-bf16 MFMA (fp32 = hi+lo bf16 RNE pair along K, K'=2K).
// R12: consolidation — exact R6 GEMM (64x128, BK=32, dbuf LDS 48KB,
//   pre-swizzled B via global_load_lds; best measured: 175us upscale, no
//   bank conflicts) + exact R10 attn (wave-per-dst, no LDS/barriers; attn
//   left top-5). R11's BK=16 halved traffic but doubled barrier steps and
//   added write conflicts -> latency-bound regression; reverted.
// ---------------------------------------------------------------------------

typedef __attribute__((ext_vector_type(8))) short bf16x8;
typedef __attribute__((ext_vector_type(4))) float f32x4;

__device__ __forceinline__ float gelu_exact(float x) {
    return 0.5f * x * (1.0f + erff(x * 0.70710678118654752f));
}

// round-to-nearest-even bf16; returns the f32 bit pattern of the rounded value
__device__ __forceinline__ unsigned int rne_bf16_bits(float f) {
    unsigned int u = __float_as_uint(f);
    unsigned int r = u + 0x7FFFu + ((u >> 16) & 1u);
    return r & 0xFFFF0000u;
}

// fp32 -> packed (hi bf16 | lo bf16<<16), RNE split.
__device__ __forceinline__ unsigned int packsplit(float f) {
    unsigned int hi_bits = rne_bf16_bits(f);
    float resid = f - __uint_as_float(hi_bits);
    unsigned int lo_bits = rne_bf16_bits(resid);
    return (hi_bits >> 16) | lo_bits;
}

// ---------------------------------------------------------------------------
// conv_wt: W[K][Bcols] fp32 -> Bt tiles, pre-swizzled LDS image (16KB/K-step).
// tile[col*64 + ((kg*8) ^ ((col&7)<<3)) + j]; gemm copies linearly w/ gload_lds.
// ---------------------------------------------------------------------------
__global__ void conv_wt(const float* __restrict__ W, ushort* __restrict__ Bt,
                        int K, int Bcols)
{
    int t = blockIdx.x * 256 + threadIdx.x;
    int KS = K >> 5;
    int total = (Bcols >> 7) * KS * 1024;
    if (t >= total) return;
    int kg    = t & 7;
    int col   = (t >> 3) & 127;
    int rest  = t >> 10;
    int kstep = rest % KS;
    int ct    = rest / KS;
    int gcol  = ct * 128 + col;
    int kbase = kstep * 32 + kg * 4;
    uint4 v;
    v.x = packsplit(W[(size_t)(kbase + 0) * Bcols + gcol]);
    v.y = packsplit(W[(size_t)(kbase + 1) * Bcols + gcol]);
    v.z = packsplit(W[(size_t)(kbase + 2) * Bcols + gcol]);
    v.w = packsplit(W[(size_t)(kbase + 3) * Bcols + gcol]);
    size_t tile = (size_t)(ct * KS + kstep) * 8192;
    *(uint4*)&Bt[tile + col * 64 + ((kg * 8) ^ ((col & 7) << 3))] = v;
}

// ---------------------------------------------------------------------------
// Split-bf16 MFMA GEMM, tile 64x128, 4 waves (2x2 of 32x64), double-buffered.
// MODE=0 (layer): blockIdx.y = column-tile ct; C[row*256 + ct*128 + col]=acc.
// MODE=1 (upscale): blockIdx.y selects {A0,B0,bias0,cb0}/{A1,B1,bias1,cb1};
//                   C[ci[row]*256 + cb + col] = gelu(acc + bias[col]).
// ---------------------------------------------------------------------------
template<int MODE>
__global__ __launch_bounds__(256)
void gemm64(const float* __restrict__ A0, const float* __restrict__ A1,
            const ushort* __restrict__ B0, const ushort* __restrict__ B1,
            const float* __restrict__ bias0, const float* __restrict__ bias1,
            float* __restrict__ C, const int* __restrict__ ci,
            int M, int K, int cb0, int cb1)
{
    __shared__ ushort As[2][64 * 64];     // 8KB per buffer
    __shared__ ushort Bs[2][128 * 64];    // 16KB per buffer

    const int tid  = threadIdx.x;
    const int lane = tid & 63;
    const int w    = tid >> 6;
    const int wr   = w >> 1, wc = w & 1;
    const int row0 = blockIdx.x * 64;
    const int KS   = K >> 5;

    const float* A; const ushort* Btile; const float* bias; int col_base, colt;
    if (MODE == 1) {
        int sel = blockIdx.y;
        A = sel ? A1 : A0; Btile = sel ? B1 : B0;
        bias = sel ? bias1 : bias0; col_base = sel ? cb1 : cb0; colt = 0;
    } else {
        A = A0; Btile = B0 + (size_t)blockIdx.y * KS * 8192;
        bias = nullptr; col_base = 0; colt = blockIdx.y * 128;
    }

    const int ar0 = tid >> 3;             // A row (p=0): 0..31
    const int ac4 = (tid & 7) * 4;        // A fp32 col within step

    f32x4 acc[2][4];
#pragma unroll
    for (int m = 0; m < 2; m++)
#pragma unroll
        for (int n = 0; n < 4; n++) acc[m][n] = (f32x4)0.f;

    auto loadA = [&](float4* rg, int ks) {
#pragma unroll
        for (int p = 0; p < 2; p++) {
            int gr = row0 + ar0 + p * 32;
            rg[p] = make_float4(0.f, 0.f, 0.f, 0.f);
            if (gr < M) rg[p] = *(const float4*)&A[(size_t)gr * K + ks * 32 + ac4];
        }
    };
    auto writeA = [&](int buf, const float4* rg) {
#pragma unroll
        for (int p = 0; p < 2; p++) {
            int r = ar0 + p * 32;
            uint4 wv;
            wv.x = packsplit(rg[p].x); wv.y = packsplit(rg[p].y);
            wv.z = packsplit(rg[p].z); wv.w = packsplit(rg[p].w);
            *(uint4*)&As[buf][r * 64 + ((2 * ac4) ^ ((r & 7) << 3))] = wv;
        }
    };
    auto stageB = [&](int buf, int ks) {
        const ushort* tp = Btile + (size_t)ks * 8192;
#pragma unroll
        for (int q = 0; q < 4; q++) {
            int off = (w * 4 + q) * 512;          // ushorts; 1KB per call
            __builtin_amdgcn_global_load_lds(
                (const __attribute__((address_space(1))) void*)(tp + off + lane * 8),
                (__attribute__((address_space(3))) void*)(&Bs[buf][off]),
                16, 0, 0);
        }
    };
    auto compute = [&](int buf) {
        bf16x8 af[2][2], bfr[4][2];
#pragma unroll
        for (int m = 0; m < 2; m++) {
            int row = wr * 32 + m * 16 + (lane & 15);
#pragma unroll
            for (int kb = 0; kb < 2; kb++) {
                int kp = kb * 32 + (lane >> 4) * 8;
                af[m][kb] = *(const bf16x8*)&As[buf][row * 64 + (kp ^ ((row & 7) << 3))];
            }
        }
#pragma unroll
        for (int n = 0; n < 4; n++) {
            int cq = wc * 64 + n * 16 + (lane & 15);
#pragma unroll
            for (int kb = 0; kb < 2; kb++) {
                int kp = kb * 32 + (lane >> 4) * 8;
                bfr[n][kb] = *(const bf16x8*)&Bs[buf][cq * 64 + (kp ^ ((cq & 7) << 3))];
            }
        }
#pragma unroll
        for (int m = 0; m < 2; m++)
#pragma unroll
            for (int n = 0; n < 4; n++) {
                acc[m][n] = __builtin_amdgcn_mfma_f32_16x16x32_bf16(
                    af[m][0], bfr[n][0], acc[m][n], 0, 0, 0);
                acc[m][n] = __builtin_amdgcn_mfma_f32_16x16x32_bf16(
                    af[m][1], bfr[n][1], acc[m][n], 0, 0, 0);
            }
    };

    // prologue: fill buffer 0, issue k=1 A loads
    float4 aprev[2];
    loadA(aprev, 0);
    stageB(0, 0);
    writeA(0, aprev);
    if (KS > 1) loadA(aprev, 1);
    __syncthreads();

    int cur = 0;
    for (int ks = 0; ks < KS - 1; ++ks) {
        int nxt = cur ^ 1;
        stageB(nxt, ks + 1);                  // async B into other buffer
        float4 anew[2];
        if (ks + 2 < KS) loadA(anew, ks + 2); // issue A two steps ahead
        writeA(nxt, aprev);                   // convert+write k+1 (regs arrived)
        compute(cur);                         // ds_read + 16 MFMA on current
        __syncthreads();
        aprev[0] = anew[0]; aprev[1] = anew[1];
        cur = nxt;
    }
    compute(cur);

    // epilogue: C/D layout col=lane&15, row=(lane>>4)*4+reg
#pragma unroll
    for (int m = 0; m < 2; m++) {
        int rbase = row0 + wr * 32 + m * 16 + ((lane >> 4) << 2);
#pragma unroll
        for (int n = 0; n < 4; n++) {
            int col = wc * 64 + n * 16 + (lane & 15);
#pragma unroll
            for (int j = 0; j < 4; j++) {
                int grow = rbase + j;
                if (grow >= M) continue;
                float v = acc[m][n][j];
                if (MODE == 1) {
                    v = gelu_exact(v + bias[col]);
                    C[(size_t)ci[grow] * 256 + col_base + col] = v;
                } else {
                    C[(size_t)grow * 256 + colt + col] = v;
                }
            }
        }
    }
}

// per-node attention scores
__global__ __launch_bounds__(256)
void scores_kernel(const float* __restrict__ h, const float* __restrict__ asrc,
                   const float* __restrict__ adst, float* __restrict__ s_src,
                   float* __restrict__ s_dst, int N)
{
    int wave = threadIdx.x >> 6;
    int lane = threadIdx.x & 63;
    int n = blockIdx.x * 4 + wave;
    if (n >= N) return;
    float4 hv = *(const float4*)&h[(size_t)n * 256 + lane * 4];
    float4 av = *(const float4*)&asrc[lane * 4];
    float4 dv = *(const float4*)&adst[lane * 4];
    float ps = hv.x * av.x + hv.y * av.y + hv.z * av.z + hv.w * av.w;
    float pd = hv.x * dv.x + hv.y * dv.y + hv.z * dv.z + hv.w * dv.w;
#pragma unroll
    for (int off = 32; off; off >>= 1) {
        ps += __shfl_xor(ps, off);
        pd += __shfl_xor(pd, off);
    }
    if (lane == 0) { s_src[n] = ps; s_dst[n] = pd; }
}

// ---- CSR build ----
__global__ void init_cnt(int* cnt, int N) {
    int i = blockIdx.x * 256 + threadIdx.x;
    if (i < N) cnt[i] = 1;
}

__global__ void count_edges(const int* __restrict__ edges, int* cnt, int E) {
    int e = blockIdx.x * 256 + threadIdx.x;
    if (e < E) atomicAdd(&cnt[edges[2 * e + 1]], 1);
}

__global__ void scan1(const int* __restrict__ cnt, int* __restrict__ rs,
                      int* __restrict__ bsum, int N)
{
    __shared__ int sm[256];
    int tid = threadIdx.x;
    int i = blockIdx.x * 256 + tid;
    int v = (i < N) ? cnt[i] : 0;
    sm[tid] = v;
    __syncthreads();
    for (int off = 1; off < 256; off <<= 1) {
        int t = (tid >= off) ? sm[tid - off] : 0;
        __syncthreads();
        sm[tid] += t;
        __syncthreads();
    }
    if (i < N) rs[i] = sm[tid] - v;
    if (tid == 255) bsum[blockIdx.x] = sm[255];
}

__global__ void scan2(int* bsum, int nb) {
    __shared__ int sm[256];
    int tid = threadIdx.x;
    int v = (tid < nb) ? bsum[tid] : 0;
    sm[tid] = v;
    __syncthreads();
    for (int off = 1; off < 256; off <<= 1) {
        int t = (tid >= off) ? sm[tid - off] : 0;
        __syncthreads();
        sm[tid] += t;
        __syncthreads();
    }
    if (tid < nb) bsum[tid] = sm[tid] - v;
}

__global__ void scan3(int* __restrict__ rs, const int* __restrict__ bsum,
                      int N, int total)
{
    int i = blockIdx.x * 256 + threadIdx.x;
    if (i < N) rs[i] += bsum[i >> 8];
    if (i == 0) rs[N] = total;
}

__global__ void copy_cursor(const int* __restrict__ rs, int* __restrict__ cur, int N) {
    int i = blockIdx.x * 256 + threadIdx.x;
    if (i < N) cur[i] = rs[i];
}

__global__ void fill_csr(const int* __restrict__ edges, int* __restrict__ cur,
                         int* __restrict__ col, int E, int N)
{
    int i = blockIdx.x * 256 + threadIdx.x;
    if (i < E) {
        int s = edges[2 * i], d = edges[2 * i + 1];
        col[atomicAdd(&cur[d], 1)] = s;
    } else if (i < E + N) {
        int n = i - E;
        col[atomicAdd(&cur[n], 1)] = n;
    }
}

// ---------------------------------------------------------------------------
// attn: WAVE per dst node. No LDS, no barriers. 64 lanes cover 256 cols
// (float4/lane); weights lane-redundant; 4-deep independent h-row gathers.
// ---------------------------------------------------------------------------
template<int EPI>
__global__ __launch_bounds__(256)
void attn_kernel(const float* __restrict__ h, const float* __restrict__ s_src,
                 const float* __restrict__ s_dst, const int* __restrict__ rs,
                 const int* __restrict__ colv, const float* __restrict__ bias,
                 float* __restrict__ out, int N)
{
    const int wv   = threadIdx.x >> 6;
    const int lane = threadIdx.x & 63;
    const int n    = blockIdx.x * 4 + wv;
    if (n >= N) return;

    const float sd = s_dst[n];
    const int beg = rs[n], end = rs[n + 1];

    float4 acc = make_float4(0.f, 0.f, 0.f, 0.f);
    float den = 0.f;

    int i = beg;
    for (; i + 3 < end; i += 4) {
        int s0 = colv[i], s1 = colv[i + 1], s2 = colv[i + 2], s3 = colv[i + 3];
        float e0 = s_src[s0] + sd, e1 = s_src[s1] + sd;
        float e2 = s_src[s2] + sd, e3 = s_src[s3] + sd;
        e0 = (e0 > 0.f) ? e0 : 0.2f * e0;  e1 = (e1 > 0.f) ? e1 : 0.2f * e1;
        e2 = (e2 > 0.f) ? e2 : 0.2f * e2;  e3 = (e3 > 0.f) ? e3 : 0.2f * e3;
        float w0 = __expf(e0), w1 = __expf(e1), w2 = __expf(e2), w3 = __expf(e3);
        float4 h0 = *(const float4*)&h[(size_t)s0 * 256 + lane * 4];
        float4 h1 = *(const float4*)&h[(size_t)s1 * 256 + lane * 4];
        float4 h2 = *(const float4*)&h[(size_t)s2 * 256 + lane * 4];
        float4 h3 = *(const float4*)&h[(size_t)s3 * 256 + lane * 4];
        acc.x = fmaf(w0, h0.x, acc.x); acc.y = fmaf(w0, h0.y, acc.y);
        acc.z = fmaf(w0, h0.z, acc.z); acc.w = fmaf(w0, h0.w, acc.w);
        acc.x = fmaf(w1, h1.x, acc.x); acc.y = fmaf(w1, h1.y, acc.y);
        acc.z = fmaf(w1, h1.z, acc.z); acc.w = fmaf(w1, h1.w, acc.w);
        acc.x = fmaf(w2, h2.x, acc.x); acc.y = fmaf(w2, h2.y, acc.y);
        acc.z = fmaf(w2, h2.z, acc.z); acc.w = fmaf(w2, h2.w, acc.w);
        acc.x = fmaf(w3, h3.x, acc.x); acc.y = fmaf(w3, h3.y, acc.y);
        acc.z = fmaf(w3, h3.z, acc.z); acc.w = fmaf(w3, h3.w, acc.w);
        den += w0 + w1 + w2 + w3;
    }
    for (; i < end; ++i) {
        int s0 = colv[i];
        float e0 = s_src[s0] + sd;
        e0 = (e0 > 0.f) ? e0 : 0.2f * e0;
        float w0 = __expf(e0);
        float4 h0 = *(const float4*)&h[(size_t)s0 * 256 + lane * 4];
        acc.x = fmaf(w0, h0.x, acc.x); acc.y = fmaf(w0, h0.y, acc.y);
        acc.z = fmaf(w0, h0.z, acc.z); acc.w = fmaf(w0, h0.w, acc.w);
        den += w0;
    }

    float4 bv = *(const float4*)&bias[lane * 4];
    float inv = 1.f / den;
    float4 v;
    v.x = acc.x * inv + bv.x; v.y = acc.y * inv + bv.y;
    v.z = acc.z * inv + bv.z; v.w = acc.w * inv + bv.w;
    if (EPI == 1) {
        v.x = gelu_exact(v.x); v.y = gelu_exact(v.y);
        v.z = gelu_exact(v.z); v.w = gelu_exact(v.w);
    } else {
        v.x = fmaxf(v.x, 0.f); v.y = fmaxf(v.y, 0.f);
        v.z = fmaxf(v.z, 0.f); v.w = fmaxf(v.w, 0.f);
    }
    *(float4*)&out[(size_t)n * 256 + lane * 4] = v;
}

extern "C" void kernel_launch(void* const* d_in, const int* in_sizes, int n_in,
                              void* d_out, int out_size, void* d_ws, size_t ws_size,
                              hipStream_t stream)
{
    const float* img    = (const float*)d_in[0];
    const float* txt    = (const float*)d_in[1];
    const int*   ci     = (const int*)d_in[2];
    const int*   edges  = (const int*)d_in[3];
    const float* w_img  = (const float*)d_in[4];
    const float* b_img  = (const float*)d_in[5];
    const float* w_text = (const float*)d_in[6];
    const float* b_text = (const float*)d_in[7];
    const float* W0     = (const float*)d_in[8];
    const float* asrc0  = (const float*)d_in[9];
    const float* adst0  = (const float*)d_in[10];
    const float* bias0  = (const float*)d_in[11];
    const float* W1     = (const float*)d_in[12];
    const float* asrc1  = (const float*)d_in[13];
    const float* adst1  = (const float*)d_in[14];
    const float* bias1  = (const float*)d_in[15];

    const int N = in_sizes[2];
    const int E = in_sizes[3] / 2;
    const int T = E + N;

    float* fA   = (float*)d_ws;                    // node, later h1   N*256
    float* fB   = fA + (size_t)N * 256;            // out0             N*256
    float* sS   = fB + (size_t)N * 256;            // N
    float* sD   = sS + N;                          // N
    int*   rs   = (int*)(sD + N);                  // N+1
    int*   cur  = rs + (N + 1);                    // N
    int*   col  = cur + N;                         // E+N
    int*   bsum = col + T;                         // <=256
    uintptr_t bt0 = ((uintptr_t)(bsum + 256) + 63) & ~(uintptr_t)63;
    ushort* BtImg = (ushort*)bt0;                  // 24 tiles x 8192
    ushort* BtTxt = BtImg + 24 * 8192;             // 24 tiles x 8192
    ushort* BtW0  = BtTxt + 24 * 8192;             // 16 tiles x 8192
    ushort* BtW1  = BtW0  + 16 * 8192;             // 16 tiles x 8192
    float* h0   = (float*)d_out;                   // N*256 scratch

    const int nb256 = (N + 255) / 256;
    const int nbT   = (T + 255) / 256;
    const int gm64  = (N + 63) / 64;               // 782

    conv_wt<<<(1 * 24 * 1024 + 255) / 256, 256, 0, stream>>>(w_img,  BtImg, 768, 128);
    conv_wt<<<(1 * 24 * 1024 + 255) / 256, 256, 0, stream>>>(w_text, BtTxt, 768, 128);
    conv_wt<<<(2 * 8  * 1024 + 255) / 256, 256, 0, stream>>>(W0,     BtW0,  256, 256);
    conv_wt<<<(2 * 8  * 1024 + 255) / 256, 256, 0, stream>>>(W1,     BtW1,  256, 256);

    // merged upscale GEMMs: grid (782, 2), y selects img/text set
    gemm64<1><<<dim3(gm64, 2), 256, 0, stream>>>(
        img, txt, BtImg, BtTxt, b_img, b_text, fA, ci, N, 768, 0, 128);

    init_cnt<<<nb256, 256, 0, stream>>>(cur, N);
    count_edges<<<(E + 255) / 256, 256, 0, stream>>>(edges, cur, E);
    scan1<<<nb256, 256, 0, stream>>>(cur, rs, bsum, N);
    scan2<<<1, 256, 0, stream>>>(bsum, nb256);
    scan3<<<nb256, 256, 0, stream>>>(rs, bsum, N, T);
    copy_cursor<<<nb256, 256, 0, stream>>>(rs, cur, N);
    fill_csr<<<nbT, 256, 0, stream>>>(edges, cur, col, E, N);

    // ---- layer 0 ----
    gemm64<0><<<dim3(gm64, 2), 256, 0, stream>>>(
        fA, nullptr, BtW0, nullptr, nullptr, nullptr, h0, nullptr, N, 256, 0, 0);
    scores_kernel<<<(N + 3) / 4, 256, 0, stream>>>(h0, asrc0, adst0, sS, sD, N);
    attn_kernel<0><<<(N + 3) / 4, 256, 0, stream>>>(h0, sS, sD, rs, col, bias0, fB, N);

    // ---- layer 1 ----
    gemm64<0><<<dim3(gm64, 2), 256, 0, stream>>>(
        fB, nullptr, BtW1, nullptr, nullptr, nullptr, fA, nullptr, N, 256, 0, 0);
    scores_kernel<<<(N + 3) / 4, 256, 0, stream>>>(fA, asrc1, adst1, sS, sD, N);
    attn_kernel<1><<<(N + 3) / 4, 256, 0, stream>>>(fA, sS, sD, rs, col, bias1, (float*)d_out, N);
}

// Round 13
// 565.291 us; speedup vs baseline: 1.0881x; 1.0437x over previous
//
#include <hip/hip_runtime.h>
#include <math.h>

// ---------------------------------------------------------------------------
// GraphConv (2-layer GAT) pipeline.
// GEMMs: split-bf16 MFMA (fp32 = hi+lo bf16 RNE pair along K, K'=2K).
// R13: R12 GEMM with 8 waves/block (512 threads). Cross-round evidence:
//   service rate tracks resident waves (R10 ~5 blk/CU -> 1.97TB/s; all
//   2 blk/CU configs -> 1.2TB/s). Same tile/traffic/pipeline as R12
//   (64x128, BK=32, dbuf LDS 48KB, pre-swizzled B via global_load_lds);
//   per-wave quadrant shrinks to 32x32 (acc 16 VGPR) so occupancy is
//   LDS-capped only: 2 blocks x 8 waves = 16 waves/CU (was 8).
// ---------------------------------------------------------------------------

typedef __attribute__((ext_vector_type(8))) short bf16x8;
typedef __attribute__((ext_vector_type(4))) float f32x4;

__device__ __forceinline__ float gelu_exact(float x) {
    return 0.5f * x * (1.0f + erff(x * 0.70710678118654752f));
}

// round-to-nearest-even bf16; returns the f32 bit pattern of the rounded value
__device__ __forceinline__ unsigned int rne_bf16_bits(float f) {
    unsigned int u = __float_as_uint(f);
    unsigned int r = u + 0x7FFFu + ((u >> 16) & 1u);
    return r & 0xFFFF0000u;
}

// fp32 -> packed (hi bf16 | lo bf16<<16), RNE split.
__device__ __forceinline__ unsigned int packsplit(float f) {
    unsigned int hi_bits = rne_bf16_bits(f);
    float resid = f - __uint_as_float(hi_bits);
    unsigned int lo_bits = rne_bf16_bits(resid);
    return (hi_bits >> 16) | lo_bits;
}

// ---------------------------------------------------------------------------
// conv_wt: W[K][Bcols] fp32 -> Bt tiles, pre-swizzled LDS image (16KB/K-step).
// tile[col*64 + ((kg*8) ^ ((col&7)<<3)) + j]; gemm copies linearly w/ gload_lds.
// ---------------------------------------------------------------------------
__global__ void conv_wt(const float* __restrict__ W, ushort* __restrict__ Bt,
                        int K, int Bcols)
{
    int t = blockIdx.x * 256 + threadIdx.x;
    int KS = K >> 5;
    int total = (Bcols >> 7) * KS * 1024;
    if (t >= total) return;
    int kg    = t & 7;
    int col   = (t >> 3) & 127;
    int rest  = t >> 10;
    int kstep = rest % KS;
    int ct    = rest / KS;
    int gcol  = ct * 128 + col;
    int kbase = kstep * 32 + kg * 4;
    uint4 v;
    v.x = packsplit(W[(size_t)(kbase + 0) * Bcols + gcol]);
    v.y = packsplit(W[(size_t)(kbase + 1) * Bcols + gcol]);
    v.z = packsplit(W[(size_t)(kbase + 2) * Bcols + gcol]);
    v.w = packsplit(W[(size_t)(kbase + 3) * Bcols + gcol]);
    size_t tile = (size_t)(ct * KS + kstep) * 8192;
    *(uint4*)&Bt[tile + col * 64 + ((kg * 8) ^ ((col & 7) << 3))] = v;
}

// ---------------------------------------------------------------------------
// Split-bf16 MFMA GEMM, tile 64x128, 8 waves (2x4 of 32x32), double-buffered.
// MODE=0 (layer): blockIdx.y = column-tile ct; C[row*256 + ct*128 + col]=acc.
// MODE=1 (upscale): blockIdx.y selects {A0,B0,bias0,cb0}/{A1,B1,bias1,cb1};
//                   C[ci[row]*256 + cb + col] = gelu(acc + bias[col]).
// ---------------------------------------------------------------------------
template<int MODE>
__global__ __launch_bounds__(512)
void gemm64(const float* __restrict__ A0, const float* __restrict__ A1,
            const ushort* __restrict__ B0, const ushort* __restrict__ B1,
            const float* __restrict__ bias0, const float* __restrict__ bias1,
            float* __restrict__ C, const int* __restrict__ ci,
            int M, int K, int cb0, int cb1)
{
    __shared__ ushort As[2][64 * 64];     // 8KB per buffer
    __shared__ ushort Bs[2][128 * 64];    // 16KB per buffer

    const int tid  = threadIdx.x;
    const int lane = tid & 63;
    const int w    = tid >> 6;            // 0..7
    const int wr   = w >> 2, wc = w & 3;  // wave -> 32x32 quadrant
    const int row0 = blockIdx.x * 64;
    const int KS   = K >> 5;

    const float* A; const ushort* Btile; const float* bias; int col_base, colt;
    if (MODE == 1) {
        int sel = blockIdx.y;
        A = sel ? A1 : A0; Btile = sel ? B1 : B0;
        bias = sel ? bias1 : bias0; col_base = sel ? cb1 : cb0; colt = 0;
    } else {
        A = A0; Btile = B0 + (size_t)blockIdx.y * KS * 8192;
        bias = nullptr; col_base = 0; colt = blockIdx.y * 128;
    }

    const int ar0 = tid >> 3;             // A row: 0..63
    const int ac4 = (tid & 7) * 4;        // A fp32 col within step

    f32x4 acc[2][2];
#pragma unroll
    for (int m = 0; m < 2; m++)
#pragma unroll
        for (int n = 0; n < 2; n++) acc[m][n] = (f32x4)0.f;

    auto loadA = [&](float4& rg, int ks) {
        int gr = row0 + ar0;
        rg = make_float4(0.f, 0.f, 0.f, 0.f);
        if (gr < M) rg = *(const float4*)&A[(size_t)gr * K + ks * 32 + ac4];
    };
    auto writeA = [&](int buf, const float4& rg) {
        int r = ar0;
        uint4 wv;
        wv.x = packsplit(rg.x); wv.y = packsplit(rg.y);
        wv.z = packsplit(rg.z); wv.w = packsplit(rg.w);
        *(uint4*)&As[buf][r * 64 + ((2 * ac4) ^ ((r & 7) << 3))] = wv;
    };
    auto stageB = [&](int buf, int ks) {
        const ushort* tp = Btile + (size_t)ks * 8192;
#pragma unroll
        for (int q = 0; q < 2; q++) {
            int off = (w * 2 + q) * 512;          // ushorts; 1KB per call
            __builtin_amdgcn_global_load_lds(
                (const __attribute__((address_space(1))) void*)(tp + off + lane * 8),
                (__attribute__((address_space(3))) void*)(&Bs[buf][off]),
                16, 0, 0);
        }
    };
    auto compute = [&](int buf) {
        bf16x8 af[2][2], bfr[2][2];
#pragma unroll
        for (int m = 0; m < 2; m++) {
            int row = wr * 32 + m * 16 + (lane & 15);
#pragma unroll
            for (int kb = 0; kb < 2; kb++) {
                int kp = kb * 32 + (lane >> 4) * 8;
                af[m][kb] = *(const bf16x8*)&As[buf][row * 64 + (kp ^ ((row & 7) << 3))];
            }
        }
#pragma unroll
        for (int n = 0; n < 2; n++) {
            int cq = wc * 32 + n * 16 + (lane & 15);
#pragma unroll
            for (int kb = 0; kb < 2; kb++) {
                int kp = kb * 32 + (lane >> 4) * 8;
                bfr[n][kb] = *(const bf16x8*)&Bs[buf][cq * 64 + (kp ^ ((cq & 7) << 3))];
            }
        }
#pragma unroll
        for (int m = 0; m < 2; m++)
#pragma unroll
            for (int n = 0; n < 2; n++) {
                acc[m][n] = __builtin_amdgcn_mfma_f32_16x16x32_bf16(
                    af[m][0], bfr[n][0], acc[m][n], 0, 0, 0);
                acc[m][n] = __builtin_amdgcn_mfma_f32_16x16x32_bf16(
                    af[m][1], bfr[n][1], acc[m][n], 0, 0, 0);
            }
    };

    // prologue: fill buffer 0, issue k=1 A loads
    float4 aprev;
    loadA(aprev, 0);
    stageB(0, 0);
    writeA(0, aprev);
    if (KS > 1) loadA(aprev, 1);
    __syncthreads();

    int cur = 0;
    for (int ks = 0; ks < KS - 1; ++ks) {
        int nxt = cur ^ 1;
        stageB(nxt, ks + 1);                  // async B into other buffer
        float4 anew;
        if (ks + 2 < KS) loadA(anew, ks + 2); // issue A two steps ahead
        writeA(nxt, aprev);                   // convert+write k+1 (regs arrived)
        compute(cur);                         // ds_read + 8 MFMA on current
        __syncthreads();
        aprev = anew;
        cur = nxt;
    }
    compute(cur);

    // epilogue: C/D layout col=lane&15, row=(lane>>4)*4+reg
#pragma unroll
    for (int m = 0; m < 2; m++) {
        int rbase = row0 + wr * 32 + m * 16 + ((lane >> 4) << 2);
#pragma unroll
        for (int n = 0; n < 2; n++) {
            int col = wc * 32 + n * 16 + (lane & 15);
#pragma unroll
            for (int j = 0; j < 4; j++) {
                int grow = rbase + j;
                if (grow >= M) continue;
                float v = acc[m][n][j];
                if (MODE == 1) {
                    v = gelu_exact(v + bias[col]);
                    C[(size_t)ci[grow] * 256 + col_base + col] = v;
                } else {
                    C[(size_t)grow * 256 + colt + col] = v;
                }
            }
        }
    }
}

// per-node attention scores
__global__ __launch_bounds__(256)
void scores_kernel(const float* __restrict__ h, const float* __restrict__ asrc,
                   const float* __restrict__ adst, float* __restrict__ s_src,
                   float* __restrict__ s_dst, int N)
{
    int wave = threadIdx.x >> 6;
    int lane = threadIdx.x & 63;
    int n = blockIdx.x * 4 + wave;
    if (n >= N) return;
    float4 hv = *(const float4*)&h[(size_t)n * 256 + lane * 4];
    float4 av = *(const float4*)&asrc[lane * 4];
    float4 dv = *(const float4*)&adst[lane * 4];
    float ps = hv.x * av.x + hv.y * av.y + hv.z * av.z + hv.w * av.w;
    float pd = hv.x * dv.x + hv.y * dv.y + hv.z * dv.z + hv.w * dv.w;
#pragma unroll
    for (int off = 32; off; off >>= 1) {
        ps += __shfl_xor(ps, off);
        pd += __shfl_xor(pd, off);
    }
    if (lane == 0) { s_src[n] = ps; s_dst[n] = pd; }
}

// ---- CSR build ----
__global__ void init_cnt(int* cnt, int N) {
    int i = blockIdx.x * 256 + threadIdx.x;
    if (i < N) cnt[i] = 1;
}

__global__ void count_edges(const int* __restrict__ edges, int* cnt, int E) {
    int e = blockIdx.x * 256 + threadIdx.x;
    if (e < E) atomicAdd(&cnt[edges[2 * e + 1]], 1);
}

__global__ void scan1(const int* __restrict__ cnt, int* __restrict__ rs,
                      int* __restrict__ bsum, int N)
{
    __shared__ int sm[256];
    int tid = threadIdx.x;
    int i = blockIdx.x * 256 + tid;
    int v = (i < N) ? cnt[i] : 0;
    sm[tid] = v;
    __syncthreads();
    for (int off = 1; off < 256; off <<= 1) {
        int t = (tid >= off) ? sm[tid - off] : 0;
        __syncthreads();
        sm[tid] += t;
        __syncthreads();
    }
    if (i < N) rs[i] = sm[tid] - v;
    if (tid == 255) bsum[blockIdx.x] = sm[255];
}

__global__ void scan2(int* bsum, int nb) {
    __shared__ int sm[256];
    int tid = threadIdx.x;
    int v = (tid < nb) ? bsum[tid] : 0;
    sm[tid] = v;
    __syncthreads();
    for (int off = 1; off < 256; off <<= 1) {
        int t = (tid >= off) ? sm[tid - off] : 0;
        __syncthreads();
        sm[tid] += t;
        __syncthreads();
    }
    if (tid < nb) bsum[tid] = sm[tid] - v;
}

__global__ void scan3(int* __restrict__ rs, const int* __restrict__ bsum,
                      int N, int total)
{
    int i = blockIdx.x * 256 + threadIdx.x;
    if (i < N) rs[i] += bsum[i >> 8];
    if (i == 0) rs[N] = total;
}

__global__ void copy_cursor(const int* __restrict__ rs, int* __restrict__ cur, int N) {
    int i = blockIdx.x * 256 + threadIdx.x;
    if (i < N) cur[i] = rs[i];
}

__global__ void fill_csr(const int* __restrict__ edges, int* __restrict__ cur,
                         int* __restrict__ col, int E, int N)
{
    int i = blockIdx.x * 256 + threadIdx.x;
    if (i < E) {
        int s = edges[2 * i], d = edges[2 * i + 1];
        col[atomicAdd(&cur[d], 1)] = s;
    } else if (i < E + N) {
        int n = i - E;
        col[atomicAdd(&cur[n], 1)] = n;
    }
}

// ---------------------------------------------------------------------------
// attn: WAVE per dst node. No LDS, no barriers. 64 lanes cover 256 cols
// (float4/lane); weights lane-redundant; 4-deep independent h-row gathers.
// ---------------------------------------------------------------------------
template<int EPI>
__global__ __launch_bounds__(256)
void attn_kernel(const float* __restrict__ h, const float* __restrict__ s_src,
                 const float* __restrict__ s_dst, const int* __restrict__ rs,
                 const int* __restrict__ colv, const float* __restrict__ bias,
                 float* __restrict__ out, int N)
{
    const int wv   = threadIdx.x >> 6;
    const int lane = threadIdx.x & 63;
    const int n    = blockIdx.x * 4 + wv;
    if (n >= N) return;

    const float sd = s_dst[n];
    const int beg = rs[n], end = rs[n + 1];

    float4 acc = make_float4(0.f, 0.f, 0.f, 0.f);
    float den = 0.f;

    int i = beg;
    for (; i + 3 < end; i += 4) {
        int s0 = colv[i], s1 = colv[i + 1], s2 = colv[i + 2], s3 = colv[i + 3];
        float e0 = s_src[s0] + sd, e1 = s_src[s1] + sd;
        float e2 = s_src[s2] + sd, e3 = s_src[s3] + sd;
        e0 = (e0 > 0.f) ? e0 : 0.2f * e0;  e1 = (e1 > 0.f) ? e1 : 0.2f * e1;
        e2 = (e2 > 0.f) ? e2 : 0.2f * e2;  e3 = (e3 > 0.f) ? e3 : 0.2f * e3;
        float w0 = __expf(e0), w1 = __expf(e1), w2 = __expf(e2), w3 = __expf(e3);
        float4 h0 = *(const float4*)&h[(size_t)s0 * 256 + lane * 4];
        float4 h1 = *(const float4*)&h[(size_t)s1 * 256 + lane * 4];
        float4 h2 = *(const float4*)&h[(size_t)s2 * 256 + lane * 4];
        float4 h3 = *(const float4*)&h[(size_t)s3 * 256 + lane * 4];
        acc.x = fmaf(w0, h0.x, acc.x); acc.y = fmaf(w0, h0.y, acc.y);
        acc.z = fmaf(w0, h0.z, acc.z); acc.w = fmaf(w0, h0.w, acc.w);
        acc.x = fmaf(w1, h1.x, acc.x); acc.y = fmaf(w1, h1.y, acc.y);
        acc.z = fmaf(w1, h1.z, acc.z); acc.w = fmaf(w1, h1.w, acc.w);
        acc.x = fmaf(w2, h2.x, acc.x); acc.y = fmaf(w2, h2.y, acc.y);
        acc.z = fmaf(w2, h2.z, acc.z); acc.w = fmaf(w2, h2.w, acc.w);
        acc.x = fmaf(w3, h3.x, acc.x); acc.y = fmaf(w3, h3.y, acc.y);
        acc.z = fmaf(w3, h3.z, acc.z); acc.w = fmaf(w3, h3.w, acc.w);
        den += w0 + w1 + w2 + w3;
    }
    for (; i < end; ++i) {
        int s0 = colv[i];
        float e0 = s_src[s0] + sd;
        e0 = (e0 > 0.f) ? e0 : 0.2f * e0;
        float w0 = __expf(e0);
        float4 h0 = *(const float4*)&h[(size_t)s0 * 256 + lane * 4];
        acc.x = fmaf(w0, h0.x, acc.x); acc.y = fmaf(w0, h0.y, acc.y);
        acc.z = fmaf(w0, h0.z, acc.z); acc.w = fmaf(w0, h0.w, acc.w);
        den += w0;
    }

    float4 bv = *(const float4*)&bias[lane * 4];
    float inv = 1.f / den;
    float4 v;
    v.x = acc.x * inv + bv.x; v.y = acc.y * inv + bv.y;
    v.z = acc.z * inv + bv.z; v.w = acc.w * inv + bv.w;
    if (EPI == 1) {
        v.x = gelu_exact(v.x); v.y = gelu_exact(v.y);
        v.z = gelu_exact(v.z); v.w = gelu_exact(v.w);
    } else {
        v.x = fmaxf(v.x, 0.f); v.y = fmaxf(v.y, 0.f);
        v.z = fmaxf(v.z, 0.f); v.w = fmaxf(v.w, 0.f);
    }
    *(float4*)&out[(size_t)n * 256 + lane * 4] = v;
}

extern "C" void kernel_launch(void* const* d_in, const int* in_sizes, int n_in,
                              void* d_out, int out_size, void* d_ws, size_t ws_size,
                              hipStream_t stream)
{
    const float* img    = (const float*)d_in[0];
    const float* txt    = (const float*)d_in[1];
    const int*   ci     = (const int*)d_in[2];
    const int*   edges  = (const int*)d_in[3];
    const float* w_img  = (const float*)d_in[4];
    const float* b_img  = (const float*)d_in[5];
    const float* w_text = (const float*)d_in[6];
    const float* b_text = (const float*)d_in[7];
    const float* W0     = (const float*)d_in[8];
    const float* asrc0  = (const float*)d_in[9];
    const float* adst0  = (const float*)d_in[10];
    const float* bias0  = (const float*)d_in[11];
    const float* W1     = (const float*)d_in[12];
    const float* asrc1  = (const float*)d_in[13];
    const float* adst1  = (const float*)d_in[14];
    const float* bias1  = (const float*)d_in[15];

    const int N = in_sizes[2];
    const int E = in_sizes[3] / 2;
    const int T = E + N;

    float* fA   = (float*)d_ws;                    // node, later h1   N*256
    float* fB   = fA + (size_t)N * 256;            // out0             N*256
    float* sS   = fB + (size_t)N * 256;            // N
    float* sD   = sS + N;                          // N
    int*   rs   = (int*)(sD + N);                  // N+1
    int*   cur  = rs + (N + 1);                    // N
    int*   col  = cur + N;                         // E+N
    int*   bsum = col + T;                         // <=256
    uintptr_t bt0 = ((uintptr_t)(bsum + 256) + 63) & ~(uintptr_t)63;
    ushort* BtImg = (ushort*)bt0;                  // 24 tiles x 8192
    ushort* BtTxt = BtImg + 24 * 8192;             // 24 tiles x 8192
    ushort* BtW0  = BtTxt + 24 * 8192;             // 16 tiles x 8192
    ushort* BtW1  = BtW0  + 16 * 8192;             // 16 tiles x 8192
    float* h0   = (float*)d_out;                   // N*256 scratch

    const int nb256 = (N + 255) / 256;
    const int nbT   = (T + 255) / 256;
    const int gm64  = (N + 63) / 64;               // 782

    conv_wt<<<(1 * 24 * 1024 + 255) / 256, 256, 0, stream>>>(w_img,  BtImg, 768, 128);
    conv_wt<<<(1 * 24 * 1024 + 255) / 256, 256, 0, stream>>>(w_text, BtTxt, 768, 128);
    conv_wt<<<(2 * 8  * 1024 + 255) / 256, 256, 0, stream>>>(W0,     BtW0,  256, 256);
    conv_wt<<<(2 * 8  * 1024 + 255) / 256, 256, 0, stream>>>(W1,     BtW1,  256, 256);

    // merged upscale GEMMs: grid (782, 2), y selects img/text set
    gemm64<1><<<dim3(gm64, 2), 512, 0, stream>>>(
        img, txt, BtImg, BtTxt, b_img, b_text, fA, ci, N, 768, 0, 128);

    init_cnt<<<nb256, 256, 0, stream>>>(cur, N);
    count_edges<<<(E + 255) / 256, 256, 0, stream>>>(edges, cur, E);
    scan1<<<nb256, 256, 0, stream>>>(cur, rs, bsum, N);
    scan2<<<1, 256, 0, stream>>>(bsum, nb256);
    scan3<<<nb256, 256, 0, stream>>>(rs, bsum, N, T);
    copy_cursor<<<nb256, 256, 0, stream>>>(rs, cur, N);
    fill_csr<<<nbT, 256, 0, stream>>>(edges, cur, col, E, N);

    // ---- layer 0 ----
    gemm64<0><<<dim3(gm64, 2), 512, 0, stream>>>(
        fA, nullptr, BtW0, nullptr, nullptr, nullptr, h0, nullptr, N, 256, 0, 0);
    scores_kernel<<<(N + 3) / 4, 256, 0, stream>>>(h0, asrc0, adst0, sS, sD, N);
    attn_kernel<0><<<(N + 3) / 4, 256, 0, stream>>>(h0, sS, sD, rs, col, bias0, fB, N);

    // ---- layer 1 ----
    gemm64<0><<<dim3(gm64, 2), 512, 0, stream>>>(
        fB, nullptr, BtW1, nullptr, nullptr, nullptr, fA, nullptr, N, 256, 0, 0);
    scores_kernel<<<(N + 3) / 4, 256, 0, stream>>>(fA, asrc1, adst1, sS, sD, N);
    attn_kernel<1><<<(N + 3) / 4, 256, 0, stream>>>(fA, sS, sD, rs, col, bias1, (float*)d_out, N);
}

// Round 14
// 551.370 us; speedup vs baseline: 1.1156x; 1.0252x over previous
//
#include <hip/hip_runtime.h>
#include <math.h>

// ---------------------------------------------------------------------------
// GraphConv (2-layer GAT) pipeline.
// GEMMs: split-bf16 MFMA (fp32 = hi+lo bf16 RNE pair along K, K'=2K).
// R14: 128-row tile to cut B-tile re-read traffic (R13 closes at ~6.1TB/s
//   aggregate service: A 307MB + B re-read 600MB + write 50MB in 158us).
//   Same BK=32, same pre-swizzled B tiles + global_load_lds, same staging
//   pattern as R12/R13 (proven 0-conflict), 512 threads = 2x4 waves of
//   64x32 quadrants, dbuf LDS 64KB -> 2 blocks/CU = 16 waves (unchanged).
//   B traffic halves (300MB); upscale logical bytes 957 -> 657MB.
// ---------------------------------------------------------------------------

typedef __attribute__((ext_vector_type(8))) short bf16x8;
typedef __attribute__((ext_vector_type(4))) float f32x4;

__device__ __forceinline__ float gelu_exact(float x) {
    return 0.5f * x * (1.0f + erff(x * 0.70710678118654752f));
}

// round-to-nearest-even bf16; returns the f32 bit pattern of the rounded value
__device__ __forceinline__ unsigned int rne_bf16_bits(float f) {
    unsigned int u = __float_as_uint(f);
    unsigned int r = u + 0x7FFFu + ((u >> 16) & 1u);
    return r & 0xFFFF0000u;
}

// fp32 -> packed (hi bf16 | lo bf16<<16), RNE split.
__device__ __forceinline__ unsigned int packsplit(float f) {
    unsigned int hi_bits = rne_bf16_bits(f);
    float resid = f - __uint_as_float(hi_bits);
    unsigned int lo_bits = rne_bf16_bits(resid);
    return (hi_bits >> 16) | lo_bits;
}

// ---------------------------------------------------------------------------
// conv_wt: W[K][Bcols] fp32 -> Bt tiles, pre-swizzled LDS image (16KB/K-step).
// tile[col*64 + ((kg*8) ^ ((col&7)<<3)) + j]; gemm copies linearly w/ gload_lds.
// (unchanged from R12/R13)
// ---------------------------------------------------------------------------
__global__ void conv_wt(const float* __restrict__ W, ushort* __restrict__ Bt,
                        int K, int Bcols)
{
    int t = blockIdx.x * 256 + threadIdx.x;
    int KS = K >> 5;
    int total = (Bcols >> 7) * KS * 1024;
    if (t >= total) return;
    int kg    = t & 7;
    int col   = (t >> 3) & 127;
    int rest  = t >> 10;
    int kstep = rest % KS;
    int ct    = rest / KS;
    int gcol  = ct * 128 + col;
    int kbase = kstep * 32 + kg * 4;
    uint4 v;
    v.x = packsplit(W[(size_t)(kbase + 0) * Bcols + gcol]);
    v.y = packsplit(W[(size_t)(kbase + 1) * Bcols + gcol]);
    v.z = packsplit(W[(size_t)(kbase + 2) * Bcols + gcol]);
    v.w = packsplit(W[(size_t)(kbase + 3) * Bcols + gcol]);
    size_t tile = (size_t)(ct * KS + kstep) * 8192;
    *(uint4*)&Bt[tile + col * 64 + ((kg * 8) ^ ((col & 7) << 3))] = v;
}

// ---------------------------------------------------------------------------
// Split-bf16 MFMA GEMM, tile 128x128, BK=32, 8 waves (2x4 of 64x32), dbuf.
// MODE=0 (layer): blockIdx.y = column-tile ct; C[row*256 + ct*128 + col]=acc.
// MODE=1 (upscale): blockIdx.y selects {A0,B0,bias0,cb0}/{A1,B1,bias1,cb1};
//                   C[ci[row]*256 + cb + col] = gelu(acc + bias[col]).
// ---------------------------------------------------------------------------
template<int MODE>
__global__ __launch_bounds__(512)
void gemm128(const float* __restrict__ A0, const float* __restrict__ A1,
             const ushort* __restrict__ B0, const ushort* __restrict__ B1,
             const float* __restrict__ bias0, const float* __restrict__ bias1,
             float* __restrict__ C, const int* __restrict__ ci,
             int M, int K, int cb0, int cb1)
{
    __shared__ ushort As[2][128 * 64];    // 16KB per buffer
    __shared__ ushort Bs[2][128 * 64];    // 16KB per buffer

    const int tid  = threadIdx.x;
    const int lane = tid & 63;
    const int w    = tid >> 6;            // 0..7
    const int wr   = w >> 2, wc = w & 3;  // wave -> 64x32 quadrant
    const int row0 = blockIdx.x * 128;
    const int KS   = K >> 5;

    const float* A; const ushort* Btile; const float* bias; int col_base, colt;
    if (MODE == 1) {
        int sel = blockIdx.y;
        A = sel ? A1 : A0; Btile = sel ? B1 : B0;
        bias = sel ? bias1 : bias0; col_base = sel ? cb1 : cb0; colt = 0;
    } else {
        A = A0; Btile = B0 + (size_t)blockIdx.y * KS * 8192;
        bias = nullptr; col_base = 0; colt = blockIdx.y * 128;
    }

    const int ar0 = tid >> 3;             // A row (p=0): 0..63
    const int ac4 = (tid & 7) * 4;        // A fp32 col within step

    f32x4 acc[4][2];
#pragma unroll
    for (int m = 0; m < 4; m++)
#pragma unroll
        for (int n = 0; n < 2; n++) acc[m][n] = (f32x4)0.f;

    auto loadA = [&](float4* rg, int ks) {
#pragma unroll
        for (int p = 0; p < 2; p++) {
            int gr = row0 + ar0 + p * 64;
            rg[p] = make_float4(0.f, 0.f, 0.f, 0.f);
            if (gr < M) rg[p] = *(const float4*)&A[(size_t)gr * K + ks * 32 + ac4];
        }
    };
    auto writeA = [&](int buf, const float4* rg) {
#pragma unroll
        for (int p = 0; p < 2; p++) {
            int r = ar0 + p * 64;
            uint4 wv;
            wv.x = packsplit(rg[p].x); wv.y = packsplit(rg[p].y);
            wv.z = packsplit(rg[p].z); wv.w = packsplit(rg[p].w);
            *(uint4*)&As[buf][r * 64 + ((2 * ac4) ^ ((r & 7) << 3))] = wv;
        }
    };
    auto stageB = [&](int buf, int ks) {
        const ushort* tp = Btile + (size_t)ks * 8192;
#pragma unroll
        for (int q = 0; q < 2; q++) {
            int off = (w * 2 + q) * 512;          // ushorts; 1KB per call
            __builtin_amdgcn_global_load_lds(
                (const __attribute__((address_space(1))) void*)(tp + off + lane * 8),
                (__attribute__((address_space(3))) void*)(&Bs[buf][off]),
                16, 0, 0);
        }
    };
    auto compute = [&](int buf) {
        bf16x8 af[4][2], bfr[2][2];
#pragma unroll
        for (int m = 0; m < 4; m++) {
            int row = wr * 64 + m * 16 + (lane & 15);
#pragma unroll
            for (int kb = 0; kb < 2; kb++) {
                int kp = kb * 32 + (lane >> 4) * 8;
                af[m][kb] = *(const bf16x8*)&As[buf][row * 64 + (kp ^ ((row & 7) << 3))];
            }
        }
#pragma unroll
        for (int n = 0; n < 2; n++) {
            int cq = wc * 32 + n * 16 + (lane & 15);
#pragma unroll
            for (int kb = 0; kb < 2; kb++) {
                int kp = kb * 32 + (lane >> 4) * 8;
                bfr[n][kb] = *(const bf16x8*)&Bs[buf][cq * 64 + (kp ^ ((cq & 7) << 3))];
            }
        }
#pragma unroll
        for (int m = 0; m < 4; m++)
#pragma unroll
            for (int n = 0; n < 2; n++) {
                acc[m][n] = __builtin_amdgcn_mfma_f32_16x16x32_bf16(
                    af[m][0], bfr[n][0], acc[m][n], 0, 0, 0);
                acc[m][n] = __builtin_amdgcn_mfma_f32_16x16x32_bf16(
                    af[m][1], bfr[n][1], acc[m][n], 0, 0, 0);
            }
    };

    // prologue: fill buffer 0, issue k=1 A loads
    float4 aprev[2];
    loadA(aprev, 0);
    stageB(0, 0);
    writeA(0, aprev);
    if (KS > 1) loadA(aprev, 1);
    __syncthreads();

    int cur = 0;
    for (int ks = 0; ks < KS - 1; ++ks) {
        int nxt = cur ^ 1;
        stageB(nxt, ks + 1);                  // async B into other buffer
        float4 anew[2];
        if (ks + 2 < KS) loadA(anew, ks + 2); // issue A two steps ahead
        writeA(nxt, aprev);                   // convert+write k+1 (regs arrived)
        compute(cur);                         // ds_read + 16 MFMA on current
        __syncthreads();
        aprev[0] = anew[0]; aprev[1] = anew[1];
        cur = nxt;
    }
    compute(cur);

    // epilogue: C/D layout col=lane&15, row=(lane>>4)*4+reg
#pragma unroll
    for (int m = 0; m < 4; m++) {
        int rbase = row0 + wr * 64 + m * 16 + ((lane >> 4) << 2);
#pragma unroll
        for (int n = 0; n < 2; n++) {
            int col = wc * 32 + n * 16 + (lane & 15);
#pragma unroll
            for (int j = 0; j < 4; j++) {
                int grow = rbase + j;
                if (grow >= M) continue;
                float v = acc[m][n][j];
                if (MODE == 1) {
                    v = gelu_exact(v + bias[col]);
                    C[(size_t)ci[grow] * 256 + col_base + col] = v;
                } else {
                    C[(size_t)grow * 256 + colt + col] = v;
                }
            }
        }
    }
}

// per-node attention scores
__global__ __launch_bounds__(256)
void scores_kernel(const float* __restrict__ h, const float* __restrict__ asrc,
                   const float* __restrict__ adst, float* __restrict__ s_src,
                   float* __restrict__ s_dst, int N)
{
    int wave = threadIdx.x >> 6;
    int lane = threadIdx.x & 63;
    int n = blockIdx.x * 4 + wave;
    if (n >= N) return;
    float4 hv = *(const float4*)&h[(size_t)n * 256 + lane * 4];
    float4 av = *(const float4*)&asrc[lane * 4];
    float4 dv = *(const float4*)&adst[lane * 4];
    float ps = hv.x * av.x + hv.y * av.y + hv.z * av.z + hv.w * av.w;
    float pd = hv.x * dv.x + hv.y * dv.y + hv.z * dv.z + hv.w * dv.w;
#pragma unroll
    for (int off = 32; off; off >>= 1) {
        ps += __shfl_xor(ps, off);
        pd += __shfl_xor(pd, off);
    }
    if (lane == 0) { s_src[n] = ps; s_dst[n] = pd; }
}

// ---- CSR build ----
__global__ void init_cnt(int* cnt, int N) {
    int i = blockIdx.x * 256 + threadIdx.x;
    if (i < N) cnt[i] = 1;
}

__global__ void count_edges(const int* __restrict__ edges, int* cnt, int E) {
    int e = blockIdx.x * 256 + threadIdx.x;
    if (e < E) atomicAdd(&cnt[edges[2 * e + 1]], 1);
}

__global__ void scan1(const int* __restrict__ cnt, int* __restrict__ rs,
                      int* __restrict__ bsum, int N)
{
    __shared__ int sm[256];
    int tid = threadIdx.x;
    int i = blockIdx.x * 256 + tid;
    int v = (i < N) ? cnt[i] : 0;
    sm[tid] = v;
    __syncthreads();
    for (int off = 1; off < 256; off <<= 1) {
        int t = (tid >= off) ? sm[tid - off] : 0;
        __syncthreads();
        sm[tid] += t;
        __syncthreads();
    }
    if (i < N) rs[i] = sm[tid] - v;
    if (tid == 255) bsum[blockIdx.x] = sm[255];
}

__global__ void scan2(int* bsum, int nb) {
    __shared__ int sm[256];
    int tid = threadIdx.x;
    int v = (tid < nb) ? bsum[tid] : 0;
    sm[tid] = v;
    __syncthreads();
    for (int off = 1; off < 256; off <<= 1) {
        int t = (tid >= off) ? sm[tid - off] : 0;
        __syncthreads();
        sm[tid] += t;
        __syncthreads();
    }
    if (tid < nb) bsum[tid] = sm[tid] - v;
}

__global__ void scan3(int* __restrict__ rs, const int* __restrict__ bsum,
                      int N, int total)
{
    int i = blockIdx.x * 256 + threadIdx.x;
    if (i < N) rs[i] += bsum[i >> 8];
    if (i == 0) rs[N] = total;
}

__global__ void copy_cursor(const int* __restrict__ rs, int* __restrict__ cur, int N) {
    int i = blockIdx.x * 256 + threadIdx.x;
    if (i < N) cur[i] = rs[i];
}

__global__ void fill_csr(const int* __restrict__ edges, int* __restrict__ cur,
                         int* __restrict__ col, int E, int N)
{
    int i = blockIdx.x * 256 + threadIdx.x;
    if (i < E) {
        int s = edges[2 * i], d = edges[2 * i + 1];
        col[atomicAdd(&cur[d], 1)] = s;
    } else if (i < E + N) {
        int n = i - E;
        col[atomicAdd(&cur[n], 1)] = n;
    }
}

// ---------------------------------------------------------------------------
// attn: WAVE per dst node. No LDS, no barriers. 64 lanes cover 256 cols
// (float4/lane); weights lane-redundant; 4-deep independent h-row gathers.
// ---------------------------------------------------------------------------
template<int EPI>
__global__ __launch_bounds__(256)
void attn_kernel(const float* __restrict__ h, const float* __restrict__ s_src,
                 const float* __restrict__ s_dst, const int* __restrict__ rs,
                 const int* __restrict__ colv, const float* __restrict__ bias,
                 float* __restrict__ out, int N)
{
    const int wv   = threadIdx.x >> 6;
    const int lane = threadIdx.x & 63;
    const int n    = blockIdx.x * 4 + wv;
    if (n >= N) return;

    const float sd = s_dst[n];
    const int beg = rs[n], end = rs[n + 1];

    float4 acc = make_float4(0.f, 0.f, 0.f, 0.f);
    float den = 0.f;

    int i = beg;
    for (; i + 3 < end; i += 4) {
        int s0 = colv[i], s1 = colv[i + 1], s2 = colv[i + 2], s3 = colv[i + 3];
        float e0 = s_src[s0] + sd, e1 = s_src[s1] + sd;
        float e2 = s_src[s2] + sd, e3 = s_src[s3] + sd;
        e0 = (e0 > 0.f) ? e0 : 0.2f * e0;  e1 = (e1 > 0.f) ? e1 : 0.2f * e1;
        e2 = (e2 > 0.f) ? e2 : 0.2f * e2;  e3 = (e3 > 0.f) ? e3 : 0.2f * e3;
        float w0 = __expf(e0), w1 = __expf(e1), w2 = __expf(e2), w3 = __expf(e3);
        float4 h0 = *(const float4*)&h[(size_t)s0 * 256 + lane * 4];
        float4 h1 = *(const float4*)&h[(size_t)s1 * 256 + lane * 4];
        float4 h2 = *(const float4*)&h[(size_t)s2 * 256 + lane * 4];
        float4 h3 = *(const float4*)&h[(size_t)s3 * 256 + lane * 4];
        acc.x = fmaf(w0, h0.x, acc.x); acc.y = fmaf(w0, h0.y, acc.y);
        acc.z = fmaf(w0, h0.z, acc.z); acc.w = fmaf(w0, h0.w, acc.w);
        acc.x = fmaf(w1, h1.x, acc.x); acc.y = fmaf(w1, h1.y, acc.y);
        acc.z = fmaf(w1, h1.z, acc.z); acc.w = fmaf(w1, h1.w, acc.w);
        acc.x = fmaf(w2, h2.x, acc.x); acc.y = fmaf(w2, h2.y, acc.y);
        acc.z = fmaf(w2, h2.z, acc.z); acc.w = fmaf(w2, h2.w, acc.w);
        acc.x = fmaf(w3, h3.x, acc.x); acc.y = fmaf(w3, h3.y, acc.y);
        acc.z = fmaf(w3, h3.z, acc.z); acc.w = fmaf(w3, h3.w, acc.w);
        den += w0 + w1 + w2 + w3;
    }
    for (; i < end; ++i) {
        int s0 = colv[i];
        float e0 = s_src[s0] + sd;
        e0 = (e0 > 0.f) ? e0 : 0.2f * e0;
        float w0 = __expf(e0);
        float4 h0 = *(const float4*)&h[(size_t)s0 * 256 + lane * 4];
        acc.x = fmaf(w0, h0.x, acc.x); acc.y = fmaf(w0, h0.y, acc.y);
        acc.z = fmaf(w0, h0.z, acc.z); acc.w = fmaf(w0, h0.w, acc.w);
        den += w0;
    }

    float4 bv = *(const float4*)&bias[lane * 4];
    float inv = 1.f / den;
    float4 v;
    v.x = acc.x * inv + bv.x; v.y = acc.y * inv + bv.y;
    v.z = acc.z * inv + bv.z; v.w = acc.w * inv + bv.w;
    if (EPI == 1) {
        v.x = gelu_exact(v.x); v.y = gelu_exact(v.y);
        v.z = gelu_exact(v.z); v.w = gelu_exact(v.w);
    } else {
        v.x = fmaxf(v.x, 0.f); v.y = fmaxf(v.y, 0.f);
        v.z = fmaxf(v.z, 0.f); v.w = fmaxf(v.w, 0.f);
    }
    *(float4*)&out[(size_t)n * 256 + lane * 4] = v;
}

extern "C" void kernel_launch(void* const* d_in, const int* in_sizes, int n_in,
                              void* d_out, int out_size, void* d_ws, size_t ws_size,
                              hipStream_t stream)
{
    const float* img    = (const float*)d_in[0];
    const float* txt    = (const float*)d_in[1];
    const int*   ci     = (const int*)d_in[2];
    const int*   edges  = (const int*)d_in[3];
    const float* w_img  = (const float*)d_in[4];
    const float* b_img  = (const float*)d_in[5];
    const float* w_text = (const float*)d_in[6];
    const float* b_text = (const float*)d_in[7];
    const float* W0     = (const float*)d_in[8];
    const float* asrc0  = (const float*)d_in[9];
    const float* adst0  = (const float*)d_in[10];
    const float* bias0  = (const float*)d_in[11];
    const float* W1     = (const float*)d_in[12];
    const float* asrc1  = (const float*)d_in[13];
    const float* adst1  = (const float*)d_in[14];
    const float* bias1  = (const float*)d_in[15];

    const int N = in_sizes[2];
    const int E = in_sizes[3] / 2;
    const int T = E + N;

    float* fA   = (float*)d_ws;                    // node, later h1   N*256
    float* fB   = fA + (size_t)N * 256;            // out0             N*256
    float* sS   = fB + (size_t)N * 256;            // N
    float* sD   = sS + N;                          // N
    int*   rs   = (int*)(sD + N);                  // N+1
    int*   cur  = rs + (N + 1);                    // N
    int*   col  = cur + N;                         // E+N
    int*   bsum = col + T;                         // <=256
    uintptr_t bt0 = ((uintptr_t)(bsum + 256) + 63) & ~(uintptr_t)63;
    ushort* BtImg = (ushort*)bt0;                  // 24 tiles x 8192
    ushort* BtTxt = BtImg + 24 * 8192;             // 24 tiles x 8192
    ushort* BtW0  = BtTxt + 24 * 8192;             // 16 tiles x 8192
    ushort* BtW1  = BtW0  + 16 * 8192;             // 16 tiles x 8192
    float* h0   = (float*)d_out;                   // N*256 scratch

    const int nb256 = (N + 255) / 256;
    const int nbT   = (T + 255) / 256;
    const int gm128 = (N + 127) / 128;             // 391

    conv_wt<<<(1 * 24 * 1024 + 255) / 256, 256, 0, stream>>>(w_img,  BtImg, 768, 128);
    conv_wt<<<(1 * 24 * 1024 + 255) / 256, 256, 0, stream>>>(w_text, BtTxt, 768, 128);
    conv_wt<<<(2 * 8  * 1024 + 255) / 256, 256, 0, stream>>>(W0,     BtW0,  256, 256);
    conv_wt<<<(2 * 8  * 1024 + 255) / 256, 256, 0, stream>>>(W1,     BtW1,  256, 256);

    // merged upscale GEMMs: grid (391, 2), y selects img/text set
    gemm128<1><<<dim3(gm128, 2), 512, 0, stream>>>(
        img, txt, BtImg, BtTxt, b_img, b_text, fA, ci, N, 768, 0, 128);

    init_cnt<<<nb256, 256, 0, stream>>>(cur, N);
    count_edges<<<(E + 255) / 256, 256, 0, stream>>>(edges, cur, E);
    scan1<<<nb256, 256, 0, stream>>>(cur, rs, bsum, N);
    scan2<<<1, 256, 0, stream>>>(bsum, nb256);
    scan3<<<nb256, 256, 0, stream>>>(rs, bsum, N, T);
    copy_cursor<<<nb256, 256, 0, stream>>>(rs, cur, N);
    fill_csr<<<nbT, 256, 0, stream>>>(edges, cur, col, E, N);

    // ---- layer 0 ----
    gemm128<0><<<dim3(gm128, 2), 512, 0, stream>>>(
        fA, nullptr, BtW0, nullptr, nullptr, nullptr, h0, nullptr, N, 256, 0, 0);
    scores_kernel<<<(N + 3) / 4, 256, 0, stream>>>(h0, asrc0, adst0, sS, sD, N);
    attn_kernel<0><<<(N + 3) / 4, 256, 0, stream>>>(h0, sS, sD, rs, col, bias0, fB, N);

    // ---- layer 1 ----
    gemm128<0><<<dim3(gm128, 2), 512, 0, stream>>>(
        fB, nullptr, BtW1, nullptr, nullptr, nullptr, fA, nullptr, N, 256, 0, 0);
    scores_kernel<<<(N + 3) / 4, 256, 0, stream>>>(fA, asrc1, adst1, sS, sD, N);
    attn_kernel<1><<<(N + 3) / 4, 256, 0, stream>>>(fA, sS, sD, rs, col, bias1, (float*)d_out, N);
}